// Round 1
// baseline (6916.373 us; speedup 1.0000x reference)
//
#include <hip/hip_runtime.h>
#include <hip/hip_cooperative_groups.h>
#include <math.h>

namespace cg = cooperative_groups;

#define T_STEPS 48
#define N_NODES 1000
#define E_EDGES 32000
#define DIN     32
#define H_DIM   64
#define G4H     256      // 4*H gates

#define NB_RECUR     250
#define NODES_PER_WG 4
#define MAX_DEG      128  // Poisson(32) in-degree; P(>128) ~ 0

// workspace offsets in 4-byte units
#define O_INDEG  0         // int[1000]
#define O_FILL   1024      // int[1000]
#define O_ROWPTR 2048      // int[1001]
#define O_CSRC   4096      // int[32000]
#define O_CNORM  36864     // f32[32000]
#define O_DINV   69632     // f32[1000]
#define O_SELF   70656     // f32[1000]
#define O_T1     71680     // f32[64000]
#define O_T2     135680    // f32[64000]
#define O_HS     199680    // f32[48*64000]

__device__ __forceinline__ float sigmf(float v) { return 1.0f / (1.0f + __expf(-v)); }

// ---------------- setup kernels ----------------
__global__ void k_count(const int* __restrict__ ei, int* __restrict__ indeg) {
  int e = blockIdx.x * 256 + threadIdx.x;
  if (e < E_EDGES) atomicAdd(&indeg[ei[E_EDGES + e]], 1);
}

__global__ void k_scan(const int* __restrict__ indeg, int* __restrict__ rowptr,
                       float* __restrict__ dinv, float* __restrict__ selfn) {
  __shared__ int sdat[1024];
  int tid = threadIdx.x;
  int v = (tid < N_NODES) ? indeg[tid] : 0;
  sdat[tid] = v;
  __syncthreads();
  for (int off = 1; off < 1024; off <<= 1) {
    int add = (tid >= off) ? sdat[tid - off] : 0;
    __syncthreads();
    sdat[tid] += add;
    __syncthreads();
  }
  if (tid < N_NODES) {
    rowptr[tid + 1] = sdat[tid];                 // inclusive scan -> rowptr[1..1000]
    float di = rsqrtf((float)(v + 1));           // deg = indeg + self loop >= 1
    dinv[tid] = di;
    selfn[tid] = di * di;
  }
  if (tid == 0) rowptr[0] = 0;
}

__global__ void k_scatter(const int* __restrict__ ei, const int* __restrict__ rowptr,
                          int* __restrict__ fill, const float* __restrict__ dinv,
                          int* __restrict__ csrc, float* __restrict__ cnorm) {
  int e = blockIdx.x * 256 + threadIdx.x;
  if (e >= E_EDGES) return;
  int s = ei[e], d = ei[E_EDGES + e];
  int pos = atomicAdd(&fill[d], 1);
  int idx = rowptr[d] + pos;
  csrc[idx] = s;
  cnorm[idx] = dinv[s] * dinv[d];
}

// ---------------- recurrence (cooperative) ----------------
__global__ void __launch_bounds__(256) k_recur(
    const float* __restrict__ x, const float* __restrict__ h0, const float* __restrict__ c0,
    const float* __restrict__ Wg1, const float* __restrict__ bg1,
    const float* __restrict__ Wg2, const float* __restrict__ bg2,
    const float* __restrict__ Wih, const float* __restrict__ Whh,
    const float* __restrict__ bih, const float* __restrict__ bhh,
    const int* __restrict__ rowptr, const int* __restrict__ csrc,
    const float* __restrict__ cnorm, const float* __restrict__ selfn,
    float* __restrict__ t1g, float* __restrict__ t2g, float* __restrict__ hsg,
    float* __restrict__ outp)
{
  cg::grid_group grid = cg::this_grid();
  const int tid = threadIdx.x;
  const int n0  = blockIdx.x * NODES_PER_WG;
  const int ln  = tid >> 6;          // local node 0..3 (one wave per node)
  const int h   = tid & 63;          // feature lane
  const int n   = n0 + ln;

  __shared__ __align__(16) float sWg1[DIN * H_DIM];
  __shared__ __align__(16) float sWg2[H_DIM * H_DIM];
  __shared__ __align__(16) float sbg1[H_DIM], sbg2[H_DIM], sbsum[G4H];
  __shared__ __align__(16) float sh[NODES_PER_WG][H_DIM], scl[NODES_PER_WG][H_DIM];
  __shared__ __align__(16) float sg1[NODES_PER_WG][H_DIM], sg2[NODES_PER_WG][H_DIM];
  __shared__ __align__(16) float sgates[NODES_PER_WG][G4H];
  __shared__ __align__(16) float sx[NODES_PER_WG][DIN];
  __shared__ int   s_esrc[NODES_PER_WG * MAX_DEG];
  __shared__ float s_ew[NODES_PER_WG * MAX_DEG];
  __shared__ int   s_ecnt[NODES_PER_WG];

  // ---- one-time preload ----
  for (int i = tid; i < DIN * H_DIM; i += 256)   sWg1[i] = Wg1[i];
  for (int i = tid; i < H_DIM * H_DIM; i += 256) sWg2[i] = Wg2[i];
  if (tid < H_DIM) { sbg1[tid] = bg1[tid]; sbg2[tid] = bg2[tid]; }
  sbsum[tid] = bih[tid] + bhh[tid];
  sh[ln][h]  = h0[n * H_DIM + h];
  scl[ln][h] = c0[n * H_DIM + h];
  if (tid < NODES_PER_WG) {
    int c = rowptr[n0 + tid + 1] - rowptr[n0 + tid];
    s_ecnt[tid] = (c > MAX_DEG) ? MAX_DEG : c;
  }
  // gate-weight rows in registers: thread j holds W_ih[j][:], W_hh[j][:]
  float4 Wih4[16], Whh4[16];
  {
    const float4* wp = (const float4*)(Wih + tid * H_DIM);
    const float4* vp = (const float4*)(Whh + tid * H_DIM);
#pragma unroll
    for (int kk = 0; kk < 16; ++kk) { Wih4[kk] = wp[kk]; Whh4[kk] = vp[kk]; }
  }
  __syncthreads();
#pragma unroll
  for (int l = 0; l < NODES_PER_WG; ++l) {
    int r0 = rowptr[n0 + l];
    int c = s_ecnt[l];
    for (int i = tid; i < c; i += 256) {
      s_esrc[l * MAX_DEG + i] = csrc[r0 + i];
      s_ew[l * MAX_DEG + i]   = cnorm[r0 + i];
    }
  }
  const float selfw = selfn[n];
  __syncthreads();

  for (int t = 0; t < T_STEPS; ++t) {
    // stage x rows for owned nodes
    if (tid < NODES_PER_WG * DIN) {
      int l = tid >> 5, k = tid & 31;
      sx[l][k] = x[(t * N_NODES + n0 + l) * DIN + k];
    }
    __syncthreads();

    // phase 1: t1 = x_t @ Wg1   (one output per thread)
    float t1acc = 0.f;
    {
      const float4* xp = (const float4*)(&sx[ln][0]);
#pragma unroll
      for (int kk = 0; kk < 8; ++kk) {
        float4 x4 = xp[kk];
        t1acc += x4.x * sWg1[(4 * kk + 0) * H_DIM + h];
        t1acc += x4.y * sWg1[(4 * kk + 1) * H_DIM + h];
        t1acc += x4.z * sWg1[(4 * kk + 2) * H_DIM + h];
        t1acc += x4.w * sWg1[(4 * kk + 3) * H_DIM + h];
      }
    }
    t1g[n * H_DIM + h] = t1acc;
    __threadfence();
    grid.sync();   // t1 visible device-wide
    __threadfence();

    // phase 2: gather1 (+bias,+relu) then t2 = g1 @ Wg2 (wave-local)
    {
      const int cnt = s_ecnt[ln];
      const int*   es = &s_esrc[ln * MAX_DEG];
      const float* ew = &s_ew[ln * MAX_DEG];
      float a0 = 0.f, a1 = 0.f, a2 = 0.f, a3 = 0.f;
      int e = 0;
      for (; e + 4 <= cnt; e += 4) {
        int q0 = es[e], q1 = es[e + 1], q2 = es[e + 2], q3 = es[e + 3];
        float w0 = ew[e], w1 = ew[e + 1], w2 = ew[e + 2], w3 = ew[e + 3];
        a0 += w0 * t1g[q0 * H_DIM + h];
        a1 += w1 * t1g[q1 * H_DIM + h];
        a2 += w2 * t1g[q2 * H_DIM + h];
        a3 += w3 * t1g[q3 * H_DIM + h];
      }
      for (; e < cnt; ++e) a0 += ew[e] * t1g[es[e] * H_DIM + h];
      float g1 = selfw * t1acc + ((a0 + a1) + (a2 + a3)) + sbg1[h];
      sg1[ln][h] = fmaxf(g1, 0.f);
    }
    float t2acc = 0.f;
    {
      const float4* gp = (const float4*)(&sg1[ln][0]);   // same wave wrote it
#pragma unroll
      for (int kk = 0; kk < 16; ++kk) {
        float4 g4 = gp[kk];
        t2acc += g4.x * sWg2[(4 * kk + 0) * H_DIM + h];
        t2acc += g4.y * sWg2[(4 * kk + 1) * H_DIM + h];
        t2acc += g4.z * sWg2[(4 * kk + 2) * H_DIM + h];
        t2acc += g4.w * sWg2[(4 * kk + 3) * H_DIM + h];
      }
    }
    t2g[n * H_DIM + h] = t2acc;
    __threadfence();
    grid.sync();   // t2 visible device-wide
    __threadfence();

    // phase 3: gather2 (+bias, no relu)
    {
      const int cnt = s_ecnt[ln];
      const int*   es = &s_esrc[ln * MAX_DEG];
      const float* ew = &s_ew[ln * MAX_DEG];
      float a0 = 0.f, a1 = 0.f, a2 = 0.f, a3 = 0.f;
      int e = 0;
      for (; e + 4 <= cnt; e += 4) {
        int q0 = es[e], q1 = es[e + 1], q2 = es[e + 2], q3 = es[e + 3];
        float w0 = ew[e], w1 = ew[e + 1], w2 = ew[e + 2], w3 = ew[e + 3];
        a0 += w0 * t2g[q0 * H_DIM + h];
        a1 += w1 * t2g[q1 * H_DIM + h];
        a2 += w2 * t2g[q2 * H_DIM + h];
        a3 += w3 * t2g[q3 * H_DIM + h];
      }
      for (; e < cnt; ++e) a0 += ew[e] * t2g[es[e] * H_DIM + h];
      sg2[ln][h] = selfw * t2acc + ((a0 + a1) + (a2 + a3)) + sbg2[h];
    }
    __syncthreads();   // all nodes' g2 + prev h ready for gates

    // phase 4: gates — thread j computes gate-row j for all 4 nodes
#pragma unroll
    for (int l2 = 0; l2 < NODES_PER_WG; ++l2) {
      float gv = sbsum[tid];
      const float4* gp = (const float4*)(&sg2[l2][0]);
      const float4* hp = (const float4*)(&sh[l2][0]);
#pragma unroll
      for (int kk = 0; kk < 16; ++kk) {
        float4 a4 = gp[kk], b4 = hp[kk];
        gv += a4.x * Wih4[kk].x + a4.y * Wih4[kk].y + a4.z * Wih4[kk].z + a4.w * Wih4[kk].w;
        gv += b4.x * Whh4[kk].x + b4.y * Whh4[kk].y + b4.z * Whh4[kk].z + b4.w * Whh4[kk].w;
      }
      sgates[l2][tid] = gv;
    }
    __syncthreads();

    // phase 5: LSTM cell update
    {
      float iv = sgates[ln][h];
      float fv = sgates[ln][64 + h];
      float gv = sgates[ln][128 + h];
      float ov = sgates[ln][192 + h];
      float cn = sigmf(fv) * scl[ln][h] + sigmf(iv) * tanhf(gv);
      float hn = sigmf(ov) * tanhf(cn);
      scl[ln][h] = cn;
      sh[ln][h] = hn;
      hsg[t * (N_NODES * H_DIM) + n * H_DIM + h] = hn;
    }
    __syncthreads();
  }

  // final hidden / cell outputs
  outp[48000 + n * H_DIM + h] = sh[ln][h];
  outp[48000 + 64000 + n * H_DIM + h] = scl[ln][h];
}

// ---------------- final projection ----------------
__global__ void k_outinit(const float* __restrict__ blin, float* __restrict__ outp) {
  int id = blockIdx.x * 256 + threadIdx.x;
  if (id < T_STEPS * N_NODES) outp[id] = blin[id % N_NODES];
}

// out[48,1000] += HS[48,64000] @ Wlin[1000,64000]^T ; 16 K-chunks x 32 n-groups
#define GEMM_MT 125
#define GEMM_NPW 32
__global__ void __launch_bounds__(256) k_gemm(const float* __restrict__ hsg,
                                              const float* __restrict__ Wlin,
                                              float* __restrict__ outp) {
  __shared__ __align__(16) float hstile[GEMM_MT * 52];   // [m][t], stride 52 (16B aligned rows)
  __shared__ float wtile[GEMM_NPW * 129];                // [n][m], stride 129 (conflict spread)
  const int tid  = threadIdx.x;
  const int kc   = blockIdx.x & 15;   // K-chunk -> XCD (bid%8) locality for HS
  const int ng   = blockIdx.x >> 4;   // n-group
  const int ks   = tid & 15;          // K slice within tile
  const int slot = tid >> 4;
  const int ngq  = slot >> 2;         // 0..3  -> 8 n each
  const int tq   = slot & 3;          // 0..3  -> 12 t each
  const int t0   = tq * 12;
  const int nb   = ngq * 8;

  float acc[8][12];
#pragma unroll
  for (int j = 0; j < 8; ++j)
#pragma unroll
    for (int u = 0; u < 12; ++u) acc[j][u] = 0.f;

  const int mchunk0 = kc * 4000;
  for (int mt = 0; mt < 32; ++mt) {
    const int m0 = mchunk0 + mt * GEMM_MT;
    for (int i = tid; i < 48 * GEMM_MT; i += 256) {
      int t_ = i / GEMM_MT;
      int m = i - t_ * GEMM_MT;
      hstile[m * 52 + t_] = hsg[t_ * 64000 + m0 + m];
    }
    for (int i = tid; i < GEMM_NPW * 128; i += 256) {
      int nl = i >> 7, m = i & 127;
      if (m < GEMM_MT) {
        int nglob = ng * GEMM_NPW + nl;
        wtile[nl * 129 + m] = (nglob < N_NODES) ? Wlin[(size_t)nglob * 64000 + m0 + m] : 0.f;
      }
    }
    __syncthreads();
#pragma unroll
    for (int it = 0; it < 8; ++it) {
      int m = ks + 16 * it;
      if (m < GEMM_MT) {
        float wv[8];
#pragma unroll
        for (int j = 0; j < 8; ++j) wv[j] = wtile[(nb + j) * 129 + m];
        const float4* hp = (const float4*)(&hstile[m * 52 + t0]);
        float4 hA = hp[0], hB = hp[1], hC = hp[2];
        float hv[12] = {hA.x, hA.y, hA.z, hA.w, hB.x, hB.y, hB.z, hB.w, hC.x, hC.y, hC.z, hC.w};
#pragma unroll
        for (int j = 0; j < 8; ++j)
#pragma unroll
          for (int u = 0; u < 12; ++u) acc[j][u] += wv[j] * hv[u];
      }
    }
    __syncthreads();
  }
  // reduce the 16 K-slices (lanes mod 16), then one atomic per output per chunk
#pragma unroll
  for (int j = 0; j < 8; ++j)
#pragma unroll
    for (int u = 0; u < 12; ++u) {
      float v = acc[j][u];
      v += __shfl_xor(v, 8, 16);
      v += __shfl_xor(v, 4, 16);
      v += __shfl_xor(v, 2, 16);
      v += __shfl_xor(v, 1, 16);
      acc[j][u] = v;
    }
  if (ks == 0) {
#pragma unroll
    for (int j = 0; j < 8; ++j) {
      int nglob = ng * GEMM_NPW + nb + j;
      if (nglob < N_NODES) {
#pragma unroll
        for (int u = 0; u < 12; ++u)
          atomicAdd(&outp[(t0 + u) * N_NODES + nglob], acc[j][u]);
      }
    }
  }
}

// ---------------- launch ----------------
extern "C" void kernel_launch(void* const* d_in, const int* in_sizes, int n_in,
                              void* d_out, int out_size, void* d_ws, size_t ws_size,
                              hipStream_t stream) {
  const float* x    = (const float*)d_in[0];
  const int*   ei   = (const int*)d_in[1];
  const float* h0   = (const float*)d_in[2];
  const float* c0   = (const float*)d_in[3];
  const float* Wg1  = (const float*)d_in[4];
  const float* bg1  = (const float*)d_in[5];
  const float* Wg2  = (const float*)d_in[6];
  const float* bg2  = (const float*)d_in[7];
  const float* Wih  = (const float*)d_in[8];
  const float* Whh  = (const float*)d_in[9];
  const float* bih  = (const float*)d_in[10];
  const float* bhh  = (const float*)d_in[11];
  const float* Wlin = (const float*)d_in[12];
  const float* blin = (const float*)d_in[13];
  float* outp = (float*)d_out;
  float* wsf  = (float*)d_ws;
  int*   wsi  = (int*)d_ws;

  int*   indeg  = wsi + O_INDEG;
  int*   fill   = wsi + O_FILL;
  int*   rowptr = wsi + O_ROWPTR;
  int*   csrc   = wsi + O_CSRC;
  float* cnorm  = wsf + O_CNORM;
  float* dinv   = wsf + O_DINV;
  float* selfn  = wsf + O_SELF;
  float* t1g    = wsf + O_T1;
  float* t2g    = wsf + O_T2;
  float* hsg    = wsf + O_HS;

  hipMemsetAsync(d_ws, 0, 8192, stream);  // indeg + fill
  k_count<<<(E_EDGES + 255) / 256, 256, 0, stream>>>(ei, indeg);
  k_scan<<<1, 1024, 0, stream>>>(indeg, rowptr, dinv, selfn);
  k_scatter<<<(E_EDGES + 255) / 256, 256, 0, stream>>>(ei, rowptr, fill, dinv, csrc, cnorm);

  {
    void* args[] = { (void*)&x, (void*)&h0, (void*)&c0, (void*)&Wg1, (void*)&bg1,
                     (void*)&Wg2, (void*)&bg2, (void*)&Wih, (void*)&Whh, (void*)&bih,
                     (void*)&bhh, (void*)&rowptr, (void*)&csrc, (void*)&cnorm,
                     (void*)&selfn, (void*)&t1g, (void*)&t2g, (void*)&hsg, (void*)&outp };
    hipLaunchCooperativeKernel((void*)k_recur, dim3(NB_RECUR), dim3(256), args, 0, stream);
  }

  k_outinit<<<(T_STEPS * N_NODES + 255) / 256, 256, 0, stream>>>(blin, outp);
  k_gemm<<<512, 256, 0, stream>>>(hsg, Wlin, outp);
}

// Round 2
// 934.171 us; speedup vs baseline: 7.4038x; 7.4038x over previous
//
#include <hip/hip_runtime.h>
#include <hip/hip_cooperative_groups.h>
#include <math.h>

namespace cg = cooperative_groups;

#define T_STEPS 48
#define N_NODES 1000
#define E_EDGES 32000
#define DIN     32
#define H_DIM   64
#define G4H     256

// ---- shared small workspace (4-byte units) ----
#define O_INDEG  0         // int[1000]
#define O_FILL   1024      // int[1000]
#define O_ROWPTR 2048      // int[1001]
#define O_CSRC   4096      // int[32000]
#define O_CNORM  36864     // f32[32000]
#define O_DINV   69632     // f32[1000]
#define O_SELF   70656     // f32[1000]
// fallback (round-1) layout
#define O_T1     71680     // f32[64000]
#define O_T2     135680    // f32[64000]
#define O_HS     199680    // f32[48*64000]
// fast-path layout
#define O_BUF0   71680                    // f32[48*64000]  T1 -> G2
#define O_BUF1   (71680 + 3072000)        // f32[48*64000]  T2 -> HS
#define WS_NEED_FAST ((size_t)(71680 + 2 * 3072000) * 4)

#define NB_RECUR     250
#define NODES_PER_WG 4
#define MAX_DEG      128

__device__ __forceinline__ float sigmf(float v) { return 1.0f / (1.0f + __expf(-v)); }

// ---------------- setup kernels (shared) ----------------
__global__ void k_count(const int* __restrict__ ei, int* __restrict__ indeg) {
  int e = blockIdx.x * 256 + threadIdx.x;
  if (e < E_EDGES) atomicAdd(&indeg[ei[E_EDGES + e]], 1);
}

__global__ void k_scan(const int* __restrict__ indeg, int* __restrict__ rowptr,
                       float* __restrict__ dinv, float* __restrict__ selfn) {
  __shared__ int sdat[1024];
  int tid = threadIdx.x;
  int v = (tid < N_NODES) ? indeg[tid] : 0;
  sdat[tid] = v;
  __syncthreads();
  for (int off = 1; off < 1024; off <<= 1) {
    int add = (tid >= off) ? sdat[tid - off] : 0;
    __syncthreads();
    sdat[tid] += add;
    __syncthreads();
  }
  if (tid < N_NODES) {
    rowptr[tid + 1] = sdat[tid];
    float di = rsqrtf((float)(v + 1));
    dinv[tid] = di;
    selfn[tid] = di * di;
  }
  if (tid == 0) rowptr[0] = 0;
}

__global__ void k_scatter(const int* __restrict__ ei, const int* __restrict__ rowptr,
                          int* __restrict__ fill, const float* __restrict__ dinv,
                          int* __restrict__ csrc, float* __restrict__ cnorm) {
  int e = blockIdx.x * 256 + threadIdx.x;
  if (e >= E_EDGES) return;
  int s = ei[e], d = ei[E_EDGES + e];
  int pos = atomicAdd(&fill[d], 1);
  int idx = rowptr[d] + pos;
  csrc[idx] = s;
  cnorm[idx] = dinv[s] * dinv[d];
}

// ================= FAST PATH (no grid syncs) =================

// T1[r, h] = x[r, :] @ Wg1 ; rows r = t*1000+n flat (48000 rows), 64 rows/block
__global__ void __launch_bounds__(256) k_t1(const float* __restrict__ x,
                                            const float* __restrict__ Wg1,
                                            float* __restrict__ T1) {
  __shared__ float sW[DIN * H_DIM];
  __shared__ float sx[4][DIN];
  const int tid = threadIdx.x, wv = tid >> 6, h = tid & 63;
  for (int i = tid; i < DIN * H_DIM; i += 256) sW[i] = Wg1[i];
  const int r0 = blockIdx.x * 64;
  for (int it = 0; it < 16; ++it) {
    __syncthreads();
    if (tid < 128) sx[tid >> 5][tid & 31] = x[(r0 + it * 4) * DIN + tid];
    __syncthreads();
    float acc = 0.f;
    const float* xr = sx[wv];
#pragma unroll
    for (int k = 0; k < DIN; ++k) acc += xr[k] * sW[k * H_DIM + h];
    T1[(r0 + it * 4 + wv) * H_DIM + h] = acc;
  }
}

// fused: G1 = relu(gather(T1)+self+bg1); T2 = G1 @ Wg2.  block: t=bid>>4, 64 nodes
__global__ void __launch_bounds__(256) k_g1t2(const float* __restrict__ T1,
                                              const float* __restrict__ Wg2,
                                              const float* __restrict__ bg1,
                                              const int* __restrict__ rowptr,
                                              const int* __restrict__ csrc,
                                              const float* __restrict__ cnorm,
                                              const float* __restrict__ selfn,
                                              float* __restrict__ T2) {
  __shared__ float sW[H_DIM * H_DIM];
  __shared__ float sg1[4][H_DIM];
  __shared__ float sb[H_DIM];
  const int tid = threadIdx.x, wv = tid >> 6, h = tid & 63;
  for (int i = tid; i < H_DIM * H_DIM; i += 256) sW[i] = Wg2[i];
  if (tid < H_DIM) sb[tid] = bg1[tid];
  __syncthreads();
  const int t = blockIdx.x >> 4, nbase = (blockIdx.x & 15) * 64;
  const float* T1t = T1 + t * (N_NODES * H_DIM);
  float* T2t = T2 + t * (N_NODES * H_DIM);
  for (int i = 0; i < 16; ++i) {
    const int n = nbase + i * 4 + wv;
    const bool valid = n < N_NODES;
    float acc = 0.f;
    if (valid) {
      const int r0v = rowptr[n];
      const int cnt = rowptr[n + 1] - r0v;
      acc = selfn[n] * T1t[n * H_DIM + h];
      for (int base = 0; base < cnt; base += 64) {
        int m = cnt - base; if (m > 64) m = 64;
        int sidx = 0; float swt = 0.f;
        if (h < m) { sidx = csrc[r0v + base + h]; swt = cnorm[r0v + base + h]; }
        for (int e = 0; e < m; ++e) {
          int s = __shfl(sidx, e);
          float ww = __shfl(swt, e);
          acc += ww * T1t[s * H_DIM + h];
        }
      }
      acc = fmaxf(acc + sb[h], 0.f);
    }
    sg1[wv][h] = acc;
    __syncthreads();
    float t2acc = 0.f;
#pragma unroll 16
    for (int k = 0; k < H_DIM; ++k) t2acc += sg1[wv][k] * sW[k * H_DIM + h];
    if (valid) T2t[n * H_DIM + h] = t2acc;
    __syncthreads();
  }
}

// G2 = gather(T2)+self+bg2
__global__ void __launch_bounds__(256) k_g2(const float* __restrict__ T2,
                                            const float* __restrict__ bg2,
                                            const int* __restrict__ rowptr,
                                            const int* __restrict__ csrc,
                                            const float* __restrict__ cnorm,
                                            const float* __restrict__ selfn,
                                            float* __restrict__ G2) {
  __shared__ float sb[H_DIM];
  const int tid = threadIdx.x, wv = tid >> 6, h = tid & 63;
  if (tid < H_DIM) sb[tid] = bg2[tid];
  __syncthreads();
  const int t = blockIdx.x >> 4, nbase = (blockIdx.x & 15) * 64;
  const float* T2t = T2 + t * (N_NODES * H_DIM);
  float* G2t = G2 + t * (N_NODES * H_DIM);
  for (int i = 0; i < 16; ++i) {
    const int n = nbase + i * 4 + wv;
    if (n >= N_NODES) continue;
    const int r0v = rowptr[n];
    const int cnt = rowptr[n + 1] - r0v;
    float acc = selfn[n] * T2t[n * H_DIM + h];
    for (int base = 0; base < cnt; base += 64) {
      int m = cnt - base; if (m > 64) m = 64;
      int sidx = 0; float swt = 0.f;
      if (h < m) { sidx = csrc[r0v + base + h]; swt = cnorm[r0v + base + h]; }
      for (int e = 0; e < m; ++e) {
        int s = __shfl(sidx, e);
        float ww = __shfl(swt, e);
        acc += ww * T2t[s * H_DIM + h];
      }
    }
    G2t[n * H_DIM + h] = acc + sb[h];
  }
}

// per-node LSTM scan: 500 blocks x 2 nodes, no inter-block sync.
// thread j holds W_ih row j and W_hh row j in registers.
__global__ void __launch_bounds__(256, 1) k_lstm(const float* __restrict__ G2,
                                                 const float* __restrict__ h0,
                                                 const float* __restrict__ c0,
                                                 const float* __restrict__ Wih,
                                                 const float* __restrict__ Whh,
                                                 const float* __restrict__ bih,
                                                 const float* __restrict__ bhh,
                                                 float* __restrict__ hsg,
                                                 float* __restrict__ outp) {
  const int tid = threadIdx.x;
  const int nb = blockIdx.x * 2;
  const int l = tid >> 6, h = tid & 63;   // meaningful for tid<128

  __shared__ float sh[2][H_DIM];
  __shared__ float sg2[2][2][H_DIM];      // [buf][node][h]
  __shared__ float sgates[2][G4H];

  float4 Wih4[16], Whh4[16];
  {
    const float4* wp = (const float4*)(Wih + tid * H_DIM);
    const float4* vp = (const float4*)(Whh + tid * H_DIM);
#pragma unroll
    for (int k = 0; k < 16; ++k) { Wih4[k] = wp[k]; Whh4[k] = vp[k]; }
  }
  const float bsum = bih[tid] + bhh[tid];
  float creg = 0.f;
  if (tid < 128) {
    sh[l][h] = h0[(nb + l) * H_DIM + h];
    creg = c0[(nb + l) * H_DIM + h];
    sg2[0][l][h] = G2[(nb + l) * H_DIM + h];   // t = 0
  }
  __syncthreads();

  for (int t = 0; t < T_STEPS; ++t) {
    const int cur = t & 1;
    float gnext = 0.f;
    if (t < T_STEPS - 1 && tid < 128)
      gnext = G2[(t + 1) * (N_NODES * H_DIM) + (nb + l) * H_DIM + h];

#pragma unroll
    for (int l2 = 0; l2 < 2; ++l2) {
      float gv = bsum;
      const float4* gp = (const float4*)(&sg2[cur][l2][0]);
      const float4* hp = (const float4*)(&sh[l2][0]);
#pragma unroll
      for (int k = 0; k < 16; ++k) {
        float4 a = gp[k], b = hp[k];
        gv += a.x * Wih4[k].x + a.y * Wih4[k].y + a.z * Wih4[k].z + a.w * Wih4[k].w;
        gv += b.x * Whh4[k].x + b.y * Whh4[k].y + b.z * Whh4[k].z + b.w * Whh4[k].w;
      }
      sgates[l2][tid] = gv;
    }
    __syncthreads();

    if (tid < 128) {
      float iv = sgates[l][h];
      float fv = sgates[l][64 + h];
      float gg = sgates[l][128 + h];
      float ov = sgates[l][192 + h];
      float cn = sigmf(fv) * creg + sigmf(iv) * tanhf(gg);
      float hn = sigmf(ov) * tanhf(cn);
      creg = cn;
      sh[l][h] = hn;
      hsg[t * (N_NODES * H_DIM) + (nb + l) * H_DIM + h] = hn;
      if (t < T_STEPS - 1) sg2[1 - cur][l][h] = gnext;
    }
    __syncthreads();
  }
  if (tid < 128) {
    outp[48000 + (nb + l) * H_DIM + h] = sh[l][h];
    outp[48000 + 64000 + (nb + l) * H_DIM + h] = creg;
  }
}

// ================= FALLBACK PATH (round-1 cooperative, known-correct) =================
__global__ void __launch_bounds__(256) k_recur(
    const float* __restrict__ x, const float* __restrict__ h0, const float* __restrict__ c0,
    const float* __restrict__ Wg1, const float* __restrict__ bg1,
    const float* __restrict__ Wg2, const float* __restrict__ bg2,
    const float* __restrict__ Wih, const float* __restrict__ Whh,
    const float* __restrict__ bih, const float* __restrict__ bhh,
    const int* __restrict__ rowptr, const int* __restrict__ csrc,
    const float* __restrict__ cnorm, const float* __restrict__ selfn,
    float* __restrict__ t1g, float* __restrict__ t2g, float* __restrict__ hsg,
    float* __restrict__ outp)
{
  cg::grid_group grid = cg::this_grid();
  const int tid = threadIdx.x;
  const int n0  = blockIdx.x * NODES_PER_WG;
  const int ln  = tid >> 6;
  const int h   = tid & 63;
  const int n   = n0 + ln;

  __shared__ __align__(16) float sWg1[DIN * H_DIM];
  __shared__ __align__(16) float sWg2[H_DIM * H_DIM];
  __shared__ __align__(16) float sbg1[H_DIM], sbg2[H_DIM], sbsum[G4H];
  __shared__ __align__(16) float sh[NODES_PER_WG][H_DIM], scl[NODES_PER_WG][H_DIM];
  __shared__ __align__(16) float sg1[NODES_PER_WG][H_DIM], sg2[NODES_PER_WG][H_DIM];
  __shared__ __align__(16) float sgates[NODES_PER_WG][G4H];
  __shared__ __align__(16) float sx[NODES_PER_WG][DIN];
  __shared__ int   s_esrc[NODES_PER_WG * MAX_DEG];
  __shared__ float s_ew[NODES_PER_WG * MAX_DEG];
  __shared__ int   s_ecnt[NODES_PER_WG];

  for (int i = tid; i < DIN * H_DIM; i += 256)   sWg1[i] = Wg1[i];
  for (int i = tid; i < H_DIM * H_DIM; i += 256) sWg2[i] = Wg2[i];
  if (tid < H_DIM) { sbg1[tid] = bg1[tid]; sbg2[tid] = bg2[tid]; }
  sbsum[tid] = bih[tid] + bhh[tid];
  sh[ln][h]  = h0[n * H_DIM + h];
  scl[ln][h] = c0[n * H_DIM + h];
  if (tid < NODES_PER_WG) {
    int c = rowptr[n0 + tid + 1] - rowptr[n0 + tid];
    s_ecnt[tid] = (c > MAX_DEG) ? MAX_DEG : c;
  }
  float4 Wih4[16], Whh4[16];
  {
    const float4* wp = (const float4*)(Wih + tid * H_DIM);
    const float4* vp = (const float4*)(Whh + tid * H_DIM);
#pragma unroll
    for (int kk = 0; kk < 16; ++kk) { Wih4[kk] = wp[kk]; Whh4[kk] = vp[kk]; }
  }
  __syncthreads();
#pragma unroll
  for (int l = 0; l < NODES_PER_WG; ++l) {
    int r0 = rowptr[n0 + l];
    int c = s_ecnt[l];
    for (int i = tid; i < c; i += 256) {
      s_esrc[l * MAX_DEG + i] = csrc[r0 + i];
      s_ew[l * MAX_DEG + i]   = cnorm[r0 + i];
    }
  }
  const float selfw = selfn[n];
  __syncthreads();

  for (int t = 0; t < T_STEPS; ++t) {
    if (tid < NODES_PER_WG * DIN) {
      int l = tid >> 5, k = tid & 31;
      sx[l][k] = x[(t * N_NODES + n0 + l) * DIN + k];
    }
    __syncthreads();
    float t1acc = 0.f;
    {
      const float4* xp = (const float4*)(&sx[ln][0]);
#pragma unroll
      for (int kk = 0; kk < 8; ++kk) {
        float4 x4 = xp[kk];
        t1acc += x4.x * sWg1[(4 * kk + 0) * H_DIM + h];
        t1acc += x4.y * sWg1[(4 * kk + 1) * H_DIM + h];
        t1acc += x4.z * sWg1[(4 * kk + 2) * H_DIM + h];
        t1acc += x4.w * sWg1[(4 * kk + 3) * H_DIM + h];
      }
    }
    t1g[n * H_DIM + h] = t1acc;
    __threadfence();
    grid.sync();
    __threadfence();
    {
      const int cnt = s_ecnt[ln];
      const int*   es = &s_esrc[ln * MAX_DEG];
      const float* ew = &s_ew[ln * MAX_DEG];
      float a0 = 0.f, a1 = 0.f, a2 = 0.f, a3 = 0.f;
      int e = 0;
      for (; e + 4 <= cnt; e += 4) {
        int q0 = es[e], q1 = es[e + 1], q2 = es[e + 2], q3 = es[e + 3];
        float w0 = ew[e], w1 = ew[e + 1], w2 = ew[e + 2], w3 = ew[e + 3];
        a0 += w0 * t1g[q0 * H_DIM + h];
        a1 += w1 * t1g[q1 * H_DIM + h];
        a2 += w2 * t1g[q2 * H_DIM + h];
        a3 += w3 * t1g[q3 * H_DIM + h];
      }
      for (; e < cnt; ++e) a0 += ew[e] * t1g[es[e] * H_DIM + h];
      float g1 = selfw * t1acc + ((a0 + a1) + (a2 + a3)) + sbg1[h];
      sg1[ln][h] = fmaxf(g1, 0.f);
    }
    float t2acc = 0.f;
    {
      const float4* gp = (const float4*)(&sg1[ln][0]);
#pragma unroll
      for (int kk = 0; kk < 16; ++kk) {
        float4 g4 = gp[kk];
        t2acc += g4.x * sWg2[(4 * kk + 0) * H_DIM + h];
        t2acc += g4.y * sWg2[(4 * kk + 1) * H_DIM + h];
        t2acc += g4.z * sWg2[(4 * kk + 2) * H_DIM + h];
        t2acc += g4.w * sWg2[(4 * kk + 3) * H_DIM + h];
      }
    }
    t2g[n * H_DIM + h] = t2acc;
    __threadfence();
    grid.sync();
    __threadfence();
    {
      const int cnt = s_ecnt[ln];
      const int*   es = &s_esrc[ln * MAX_DEG];
      const float* ew = &s_ew[ln * MAX_DEG];
      float a0 = 0.f, a1 = 0.f, a2 = 0.f, a3 = 0.f;
      int e = 0;
      for (; e + 4 <= cnt; e += 4) {
        int q0 = es[e], q1 = es[e + 1], q2 = es[e + 2], q3 = es[e + 3];
        float w0 = ew[e], w1 = ew[e + 1], w2 = ew[e + 2], w3 = ew[e + 3];
        a0 += w0 * t2g[q0 * H_DIM + h];
        a1 += w1 * t2g[q1 * H_DIM + h];
        a2 += w2 * t2g[q2 * H_DIM + h];
        a3 += w3 * t2g[q3 * H_DIM + h];
      }
      for (; e < cnt; ++e) a0 += ew[e] * t2g[es[e] * H_DIM + h];
      sg2[ln][h] = selfw * t2acc + ((a0 + a1) + (a2 + a3)) + sbg2[h];
    }
    __syncthreads();
#pragma unroll
    for (int l2 = 0; l2 < NODES_PER_WG; ++l2) {
      float gv = sbsum[tid];
      const float4* gp = (const float4*)(&sg2[l2][0]);
      const float4* hp = (const float4*)(&sh[l2][0]);
#pragma unroll
      for (int kk = 0; kk < 16; ++kk) {
        float4 a4 = gp[kk], b4 = hp[kk];
        gv += a4.x * Wih4[kk].x + a4.y * Wih4[kk].y + a4.z * Wih4[kk].z + a4.w * Wih4[kk].w;
        gv += b4.x * Whh4[kk].x + b4.y * Whh4[kk].y + b4.z * Whh4[kk].z + b4.w * Whh4[kk].w;
      }
      sgates[l2][tid] = gv;
    }
    __syncthreads();
    {
      float iv = sgates[ln][h];
      float fv = sgates[ln][64 + h];
      float gv = sgates[ln][128 + h];
      float ov = sgates[ln][192 + h];
      float cn = sigmf(fv) * scl[ln][h] + sigmf(iv) * tanhf(gv);
      float hn = sigmf(ov) * tanhf(cn);
      scl[ln][h] = cn;
      sh[ln][h] = hn;
      hsg[t * (N_NODES * H_DIM) + n * H_DIM + h] = hn;
    }
    __syncthreads();
  }
  outp[48000 + n * H_DIM + h] = sh[ln][h];
  outp[48000 + 64000 + n * H_DIM + h] = scl[ln][h];
}

// ---------------- final projection (shared) ----------------
__global__ void k_outinit(const float* __restrict__ blin, float* __restrict__ outp) {
  int id = blockIdx.x * 256 + threadIdx.x;
  if (id < T_STEPS * N_NODES) outp[id] = blin[id % N_NODES];
}

#define GEMM_MT 125
#define GEMM_NPW 32
__global__ void __launch_bounds__(256) k_gemm(const float* __restrict__ hsg,
                                              const float* __restrict__ Wlin,
                                              float* __restrict__ outp) {
  __shared__ __align__(16) float hstile[GEMM_MT * 52];
  __shared__ float wtile[GEMM_NPW * 129];
  const int tid  = threadIdx.x;
  const int kc   = blockIdx.x & 15;
  const int ng   = blockIdx.x >> 4;
  const int ks   = tid & 15;
  const int slot = tid >> 4;
  const int ngq  = slot >> 2;
  const int tq   = slot & 3;
  const int t0   = tq * 12;
  const int nb   = ngq * 8;

  float acc[8][12];
#pragma unroll
  for (int j = 0; j < 8; ++j)
#pragma unroll
    for (int u = 0; u < 12; ++u) acc[j][u] = 0.f;

  const int mchunk0 = kc * 4000;
  for (int mt = 0; mt < 32; ++mt) {
    const int m0 = mchunk0 + mt * GEMM_MT;
    for (int i = tid; i < 48 * GEMM_MT; i += 256) {
      int t_ = i / GEMM_MT;
      int m = i - t_ * GEMM_MT;
      hstile[m * 52 + t_] = hsg[t_ * 64000 + m0 + m];
    }
    for (int i = tid; i < GEMM_NPW * 128; i += 256) {
      int nl = i >> 7, m = i & 127;
      if (m < GEMM_MT) {
        int nglob = ng * GEMM_NPW + nl;
        wtile[nl * 129 + m] = (nglob < N_NODES) ? Wlin[(size_t)nglob * 64000 + m0 + m] : 0.f;
      }
    }
    __syncthreads();
#pragma unroll
    for (int it = 0; it < 8; ++it) {
      int m = ks + 16 * it;
      if (m < GEMM_MT) {
        float wv[8];
#pragma unroll
        for (int j = 0; j < 8; ++j) wv[j] = wtile[(nb + j) * 129 + m];
        const float4* hp = (const float4*)(&hstile[m * 52 + t0]);
        float4 hA = hp[0], hB = hp[1], hC = hp[2];
        float hv[12] = {hA.x, hA.y, hA.z, hA.w, hB.x, hB.y, hB.z, hB.w, hC.x, hC.y, hC.z, hC.w};
#pragma unroll
        for (int j = 0; j < 8; ++j)
#pragma unroll
          for (int u = 0; u < 12; ++u) acc[j][u] += wv[j] * hv[u];
      }
    }
    __syncthreads();
  }
#pragma unroll
  for (int j = 0; j < 8; ++j)
#pragma unroll
    for (int u = 0; u < 12; ++u) {
      float v = acc[j][u];
      v += __shfl_xor(v, 8, 16);
      v += __shfl_xor(v, 4, 16);
      v += __shfl_xor(v, 2, 16);
      v += __shfl_xor(v, 1, 16);
      acc[j][u] = v;
    }
  if (ks == 0) {
#pragma unroll
    for (int j = 0; j < 8; ++j) {
      int nglob = ng * GEMM_NPW + nb + j;
      if (nglob < N_NODES) {
#pragma unroll
        for (int u = 0; u < 12; ++u)
          atomicAdd(&outp[(t0 + u) * N_NODES + nglob], acc[j][u]);
      }
    }
  }
}

// ---------------- launch ----------------
extern "C" void kernel_launch(void* const* d_in, const int* in_sizes, int n_in,
                              void* d_out, int out_size, void* d_ws, size_t ws_size,
                              hipStream_t stream) {
  const float* x    = (const float*)d_in[0];
  const int*   ei   = (const int*)d_in[1];
  const float* h0   = (const float*)d_in[2];
  const float* c0   = (const float*)d_in[3];
  const float* Wg1  = (const float*)d_in[4];
  const float* bg1  = (const float*)d_in[5];
  const float* Wg2  = (const float*)d_in[6];
  const float* bg2  = (const float*)d_in[7];
  const float* Wih  = (const float*)d_in[8];
  const float* Whh  = (const float*)d_in[9];
  const float* bih  = (const float*)d_in[10];
  const float* bhh  = (const float*)d_in[11];
  const float* Wlin = (const float*)d_in[12];
  const float* blin = (const float*)d_in[13];
  float* outp = (float*)d_out;
  float* wsf  = (float*)d_ws;
  int*   wsi  = (int*)d_ws;

  int*   indeg  = wsi + O_INDEG;
  int*   fill   = wsi + O_FILL;
  int*   rowptr = wsi + O_ROWPTR;
  int*   csrc   = wsi + O_CSRC;
  float* cnorm  = wsf + O_CNORM;
  float* dinv   = wsf + O_DINV;
  float* selfn  = wsf + O_SELF;

  hipMemsetAsync(d_ws, 0, 8192, stream);  // indeg + fill
  k_count<<<(E_EDGES + 255) / 256, 256, 0, stream>>>(ei, indeg);
  k_scan<<<1, 1024, 0, stream>>>(indeg, rowptr, dinv, selfn);
  k_scatter<<<(E_EDGES + 255) / 256, 256, 0, stream>>>(ei, rowptr, fill, dinv, csrc, cnorm);

  if (ws_size >= WS_NEED_FAST) {
    // ---- fast decomposed path ----
    float* buf0 = wsf + O_BUF0;   // T1 -> G2
    float* buf1 = wsf + O_BUF1;   // T2 -> HS
    k_t1<<<750, 256, 0, stream>>>(x, Wg1, buf0);
    k_g1t2<<<768, 256, 0, stream>>>(buf0, Wg2, bg1, rowptr, csrc, cnorm, selfn, buf1);
    k_g2<<<768, 256, 0, stream>>>(buf1, bg2, rowptr, csrc, cnorm, selfn, buf0);
    k_lstm<<<500, 256, 0, stream>>>(buf0, h0, c0, Wih, Whh, bih, bhh, buf1, outp);
    k_outinit<<<(T_STEPS * N_NODES + 255) / 256, 256, 0, stream>>>(blin, outp);
    k_gemm<<<512, 256, 0, stream>>>(buf1, Wlin, outp);
  } else {
    // ---- fallback: round-1 cooperative path ----
    float* t1g = wsf + O_T1;
    float* t2g = wsf + O_T2;
    float* hsg = wsf + O_HS;
    void* args[] = { (void*)&x, (void*)&h0, (void*)&c0, (void*)&Wg1, (void*)&bg1,
                     (void*)&Wg2, (void*)&bg2, (void*)&Wih, (void*)&Whh, (void*)&bih,
                     (void*)&bhh, (void*)&rowptr, (void*)&csrc, (void*)&cnorm,
                     (void*)&selfn, (void*)&t1g, (void*)&t2g, (void*)&hsg, (void*)&outp };
    hipLaunchCooperativeKernel((void*)k_recur, dim3(NB_RECUR), dim3(256), args, 0, stream);
    k_outinit<<<(T_STEPS * N_NODES + 255) / 256, 256, 0, stream>>>(blin, outp);
    k_gemm<<<512, 256, 0, stream>>>(wsf + O_HS, Wlin, outp);
  }
}